// Round 7
// baseline (135.202 us; speedup 1.0000x reference)
//
#include <hip/hip_runtime.h>
#include <hip/hip_bf16.h>

#define B_ 8
#define L_ 2048
#define D_ 128
#define BL_ (B_ * L_)
#define DELTA2 0.016f   // 2*delta; delta=0.008 >= rigorous bf16 dot bound (0.004) with 2x margin
#define QCAP 1024       // measured candidate load ~70/block -> 14x margin

typedef __attribute__((ext_vector_type(8))) short bf16x8;
typedef __attribute__((ext_vector_type(4))) float f32x4;

__device__ __forceinline__ void gload_lds16(const void* g, void* l) {
    __builtin_amdgcn_global_load_lds(
        (const __attribute__((address_space(1))) unsigned int*)g,
        (__attribute__((address_space(3))) unsigned int*)l, 16, 0, 0);
}

#define WAIT_VM(N) asm volatile("s_waitcnt vmcnt(" #N ")" ::: "memory")

// ---------------- K1: normalize + bf16 cast (round-0 linear mapping, proven) ----------------
__global__ void k_norm(const float* __restrict__ ctx,
                       float* __restrict__ cn, float* __restrict__ en,
                       ushort* __restrict__ cnb, ushort* __restrict__ enb) {
    int wid  = blockIdx.x * 4 + (threadIdx.x >> 6);   // 0..32767
    int lane = threadIdx.x & 63;
    int b   = wid >> 12;
    int rem = wid & 4095;
    int c   = rem >> 11;
    int l   = rem & 2047;

    const float* src = ctx + (size_t)wid * D_;
    float2 v = ((const float2*)src)[lane];
    float ss = v.x * v.x + v.y * v.y;
    #pragma unroll
    for (int off = 32; off; off >>= 1) ss += __shfl_down(ss, off, 64);
    ss = __shfl(ss, 0, 64);
    float n = fmaxf(sqrtf(ss), 1e-8f);
    float ox = v.x / n, oy = v.y / n;

    size_t ro = (size_t)(b * L_ + l) * D_;
    float* dst = (c == 0 ? cn : en) + ro;
    ((float2*)dst)[lane] = make_float2(ox, oy);

    __hip_bfloat16 hx = __float2bfloat16(ox), hy = __float2bfloat16(oy);
    ushort ux = *(ushort*)&hx, uy = *(ushort*)&hy;
    ushort* dstb = (c == 0 ? cnb : enb) + ro;
    ((ushort2*)dstb)[lane] = make_ushort2(ux, uy);
}

// ---------------- K2: fused sim + argmax, 1024 threads (16 waves = 4/SIMD) ----------------
// grid 256: b = blk&7, rb = blk>>3. Block = 64 rows x 2048 cols -- SAME arithmetic
// intensity as the verified 8-wave version (each wave holds all 64 A-rows in regs),
// but 16 waves double per-SIMD TLP and per-CU in-flight loads for the latency-bound
// B stream. Wave w owns cols [w*128,+128) = 8 chunks of 16 cols, ring depth 2,
// counted vmcnt, no barriers in the hot loop. 2-pass screen + exact f64 repair.
__global__ __launch_bounds__(1024, 4) void k_sim(
        const ushort* __restrict__ cnb, const ushort* __restrict__ enb,
        const float* __restrict__ cn,  const float* __restrict__ en,
        int* __restrict__ finalidx) {
    __shared__ __align__(16) char ring[16][2][4096];   // 128 KB
    __shared__ float wrowmax[16][64];
    __shared__ float rowth_l[64];
    __shared__ unsigned long long best[64];
    __shared__ int qbuf[QCAP];
    __shared__ int qn;

    const int bid = blockIdx.x;
    const int b = bid & 7, rb = bid >> 3;
    const int row0 = rb * 64;
    const int tid = threadIdx.x;
    const int wave = tid >> 6, lane = tid & 63;
    const int m = lane & 15, q = lane >> 4;

    if (tid == 0) qn = 0;
    if (tid < 64) best[tid] = 0ULL;

    const ushort* Ab = cnb + ((size_t)(b * L_) + row0) * D_;
    const char* gw = (const char*)(enb + (size_t)(b * L_) * D_) + (size_t)wave * 32768;
    char* Bw = &ring[wave][0][0];

    // A fragments: 64 rows x 128 k in registers (64 VGPRs, whole kernel)
    bf16x8 Areg[16];
    #pragma unroll
    for (int rt = 0; rt < 4; ++rt)
        #pragma unroll
        for (int kc = 0; kc < 4; ++kc)
            Areg[rt * 4 + kc] = *(const bf16x8*)(Ab + (size_t)(rt * 16 + m) * D_ + kc * 32 + q * 8);

    // stage chunk c (16 cols = 4KB) into ring slot c&1, pre-swizzled global source
    auto STAGE = [&](int c) {
        const char* gc = gw + (size_t)c * 4096;
        char* lbuf = Bw + (c & 1) * 4096;
        #pragma unroll
        for (int i = 0; i < 4; ++i) {
            int j = i * 4 + q;                               // col within chunk
            int so = j * 256 + ((m ^ (j & 7)) << 4);         // swizzled source
            gload_lds16(gc + so, lbuf + i * 1024);           // linear LDS dest
        }
    };
    // 64 rows x 16 cols x 128 k; swizzled ds_read
    auto TILE = [&](int c, f32x4 acc[4]) {
        const char* lbuf = Bw + (c & 1) * 4096;
        #pragma unroll
        for (int rt = 0; rt < 4; ++rt) acc[rt] = (f32x4){0.f, 0.f, 0.f, 0.f};
        #pragma unroll
        for (int kc = 0; kc < 4; ++kc) {
            bf16x8 bf = *(const bf16x8*)(lbuf + m * 256 + ((kc * 64 + q * 16) ^ ((m & 7) << 4)));
            #pragma unroll
            for (int rt = 0; rt < 4; ++rt)
                acc[rt] = __builtin_amdgcn_mfma_f32_16x16x32_bf16(Areg[rt * 4 + kc], bf, acc[rt], 0, 0, 0);
        }
    };

    float runmax[16];
    #pragma unroll
    for (int s = 0; s < 16; ++s) runmax[s] = -3.0e38f;

    auto FMAX = [&](const f32x4 acc[4]) {
        #pragma unroll
        for (int rt = 0; rt < 4; ++rt)
            #pragma unroll
            for (int reg = 0; reg < 4; ++reg)
                runmax[rt * 4 + reg] = fmaxf(runmax[rt * 4 + reg], acc[rt][reg]);
    };

    // ---------------- PASS 1 (forward): rowmax only ----------------
    STAGE(0); STAGE(1);
    #pragma unroll 1
    for (int c = 0; c < 6; ++c) {
        WAIT_VM(4);                                    // stage c retired
        f32x4 acc[4];
        TILE(c, acc);
        STAGE(c + 2);                                  // slot c&1 just freed
        FMAX(acc);
    }
    { WAIT_VM(4); f32x4 acc[4]; TILE(6, acc); FMAX(acc); }
    { WAIT_VM(0); f32x4 acc[4]; TILE(7, acc); FMAX(acc); }

    // cross-lane (m) then cross-wave row-max reduction
    #pragma unroll
    for (int s = 0; s < 16; ++s) {
        float v = runmax[s];
        v = fmaxf(v, __shfl_xor(v, 1, 64));
        v = fmaxf(v, __shfl_xor(v, 2, 64));
        v = fmaxf(v, __shfl_xor(v, 4, 64));
        v = fmaxf(v, __shfl_xor(v, 8, 64));
        runmax[s] = v;
    }
    if (m == 0) {
        #pragma unroll
        for (int rt = 0; rt < 4; ++rt)
            #pragma unroll
            for (int reg = 0; reg < 4; ++reg)
                wrowmax[wave][rt * 16 + q * 4 + reg] = runmax[rt * 4 + reg];
    }
    __syncthreads();
    if (tid < 64) {
        float rm = wrowmax[0][tid];
        #pragma unroll
        for (int w = 1; w < 16; ++w) rm = fmaxf(rm, wrowmax[w][tid]);
        rowth_l[tid] = rm - DELTA2;
    }
    __syncthreads();
    float rowth_r[16];
    #pragma unroll
    for (int rt = 0; rt < 4; ++rt)
        #pragma unroll
        for (int reg = 0; reg < 4; ++reg)
            rowth_r[rt * 4 + reg] = rowth_l[rt * 16 + q * 4 + reg];

    auto CAPT = [&](int c, const f32x4 acc[4]) {
        int col = wave * 128 + c * 16 + m;
        #pragma unroll
        for (int rt = 0; rt < 4; ++rt)
            #pragma unroll
            for (int reg = 0; reg < 4; ++reg)
                if (acc[rt][reg] >= rowth_r[rt * 4 + reg]) {
                    int row = rt * 16 + q * 4 + reg;
                    int pos = atomicAdd(&qn, 1);
                    if (pos < QCAP) qbuf[pos] = (row << 12) | col;
                }
    };

    // ---------------- PASS 2 (reverse): recompute + capture ----------------
    // chunks 7 (slot1), 6 (slot0) still resident from pass 1.
    { f32x4 acc[4]; TILE(7, acc); STAGE(5); CAPT(7, acc); }
    { f32x4 acc[4]; TILE(6, acc); STAGE(4); CAPT(6, acc); }
    #pragma unroll 1
    for (int d = 2; d < 6; ++d) {
        WAIT_VM(4);                                    // stage for chunk 7-d retired
        f32x4 acc[4];
        TILE(7 - d, acc);
        STAGE(5 - d);
        CAPT(7 - d, acc);
    }
    { WAIT_VM(4); f32x4 acc[4]; TILE(1, acc); CAPT(1, acc); }
    { WAIT_VM(0); f32x4 acc[4]; TILE(0, acc); CAPT(0, acc); }
    __syncthreads();

    // ---------------- PASS 3: exact double dots, 4 candidates/wave ----------------
    int qtot = min(qn, QCAP);
    for (int e0 = wave * 4; e0 < qtot; e0 += 64) {
        int e = e0 + q;
        bool act = (e < qtot);
        int pc = qbuf[act ? e : (qtot - 1)];
        int rl = (pc >> 12) & 63, col = pc & 0xFFF;
        const float* ar = cn + ((size_t)(b * L_) + row0 + rl) * D_;
        const float* br = en + ((size_t)(b * L_) + col) * D_;
        float4 x0 = ((const float4*)ar)[m * 2], x1 = ((const float4*)ar)[m * 2 + 1];
        float4 y0 = ((const float4*)br)[m * 2], y1 = ((const float4*)br)[m * 2 + 1];
        double s = (double)x0.x * y0.x + (double)x0.y * y0.y +
                   (double)x0.z * y0.z + (double)x0.w * y0.w +
                   (double)x1.x * y1.x + (double)x1.y * y1.y +
                   (double)x1.z * y1.z + (double)x1.w * y1.w;
        s += __shfl_xor(s, 1, 64);
        s += __shfl_xor(s, 2, 64);
        s += __shfl_xor(s, 4, 64);
        s += __shfl_xor(s, 8, 64);
        if (act && m == 0) {
            unsigned long long ub = (unsigned long long)__double_as_longlong(s);
            ub = (ub & 0x8000000000000000ULL) ? ~ub : (ub | 0x8000000000000000ULL);
            ub = (ub & ~0x7FFULL) | (unsigned long long)(2047 - col);  // tie -> lowest col
            atomicMax(&best[rl], ub);
        }
    }
    __syncthreads();
    if (tid < 64)
        finalidx[b * L_ + row0 + tid] = 2047 - (int)(best[tid] & 0x7FFULL);
}

// ---------------- K3: fused MLP + output (round-5 structure) ----------------
__global__ __launch_bounds__(256) void k_mlp(
        const float* __restrict__ cn, const float* __restrict__ en,
        const int* __restrict__ finalidx,
        const float* __restrict__ W1, const float* __restrict__ b1,
        const float* __restrict__ W2, const float* __restrict__ b2,
        float* __restrict__ out) {
    __shared__ __align__(16) float As[32][132];
    __shared__ __align__(16) float Bs[32][132];
    __shared__ float redv[128][16];
    __shared__ float sumv[128];
    __shared__ int fidxs[64];

    int tid = threadIdx.x;
    int tx = tid & 15, ty = tid >> 4;
    int r  = tid >> 3, kg = tid & 7;
    int bid = blockIdx.x;
    int b = bid & 7, rb = bid >> 3;
    int row0 = rb * 64;

    if (tid < 64) fidxs[tid] = finalidx[b * L_ + row0 + tid];

    const float* cnb_ = cn + ((size_t)(b * L_) + row0) * D_;
    const float* enb_ = en + (size_t)(b * L_) * D_;

    float acc[8][8];
    #pragma unroll
    for (int i = 0; i < 8; ++i)
        #pragma unroll
        for (int j = 0; j < 8; ++j) acc[i][j] = 0.0f;

    for (int kc = 0; kc < 4; ++kc) {
        __syncthreads();                       // also covers fidxs on kc==0
        #pragma unroll
        for (int p = 0; p < 4; ++p) {
            int rr = r + 32 * p;
            const float* srow = (rr < 64) ? (cnb_ + (size_t)rr * D_)
                                          : (enb_ + (size_t)fidxs[rr - 64] * D_);
            float4 v = *(const float4*)(srow + kc * 32 + kg * 4);
            As[kg][rr]      = v.x;
            As[8 + kg][rr]  = v.y;
            As[16 + kg][rr] = v.z;
            As[24 + kg][rr] = v.w;
        }
        {
            int kr = r, phys = (kr & 3) * 8 + (kr >> 2);
            const float* srcp = W1 + (size_t)(kc * 32 + kr) * D_ + kg * 16;
            #pragma unroll
            for (int qq = 0; qq < 4; ++qq)
                *(float4*)&Bs[phys][kg * 16 + qq * 4] = *(const float4*)(srcp + qq * 4);
        }
        __syncthreads();
        #pragma unroll
        for (int k = 0; k < 32; ++k) {
            float a[8], bb[8];
            *(float4*)&a[0]  = *(const float4*)&As[k][ty * 4];
            *(float4*)&a[4]  = *(const float4*)&As[k][64 + ty * 4];
            *(float4*)&bb[0] = *(const float4*)&Bs[k][tx * 4];
            *(float4*)&bb[4] = *(const float4*)&Bs[k][64 + tx * 4];
            #pragma unroll
            for (int i = 0; i < 8; ++i)
                #pragma unroll
                for (int j = 0; j < 8; ++j)
                    acc[i][j] = fmaf(a[i], bb[j], acc[i][j]);
        }
    }

    float w2j[8], b1j[8];
    #pragma unroll
    for (int jj = 0; jj < 8; ++jj) {
        int c = (jj < 4) ? (tx * 4 + jj) : (64 + tx * 4 + (jj - 4));
        w2j[jj] = W2[c];
        b1j[jj] = b1[c];
    }
    float bias2 = b2[0];
    __syncthreads();
    #pragma unroll
    for (int i = 0; i < 8; ++i) {
        float s = 0.0f;
        #pragma unroll
        for (int jj = 0; jj < 8; ++jj)
            s += fmaxf(acc[i][jj] + b1j[jj], 0.0f) * w2j[jj];
        int rowl = (i < 4) ? (ty * 4 + i) : (64 + ty * 4 + (i - 4));
        redv[rowl][tx] = s;
    }
    __syncthreads();
    if (tid < 128) {
        float s = 0.0f;
        #pragma unroll
        for (int tt = 0; tt < 16; ++tt) s += redv[tid][tt];
        sumv[tid] = s + bias2;
    }
    __syncthreads();
    if (tid < 64)
        out[b * L_ + row0 + tid] = sumv[tid] + sumv[64 + tid];
}

extern "C" void kernel_launch(void* const* d_in, const int* in_sizes, int n_in,
                              void* d_out, int out_size, void* d_ws, size_t ws_size,
                              hipStream_t stream) {
    const float* context = (const float*)d_in[0];
    const float* W1 = (const float*)d_in[1];
    const float* b1 = (const float*)d_in[2];
    const float* W2 = (const float*)d_in[3];
    const float* b2 = (const float*)d_in[4];
    float* out = (float*)d_out;

    char* ws = (char*)d_ws;
    float*  cn  = (float*)(ws);                  // 8 MB
    float*  en  = (float*)(ws + 8388608);        // 8 MB
    ushort* cnb = (ushort*)(ws + 16777216);      // 4 MB
    ushort* enb = (ushort*)(ws + 20971520);      // 4 MB
    int* finalidx = (int*)(ws + 25165824);       // 64 KB

    k_norm<<<8192, 256, 0, stream>>>(context, cn, en, cnb, enb);
    k_sim<<<256, 1024, 0, stream>>>(cnb, enb, cn, en, finalidx);
    k_mlp<<<256, 256, 0, stream>>>(cn, en, finalidx, W1, b1, W2, b2, out);
}

// Round 8
// 124.838 us; speedup vs baseline: 1.0830x; 1.0830x over previous
//
#include <hip/hip_runtime.h>
#include <hip/hip_bf16.h>

#define B_ 8
#define L_ 2048
#define D_ 128
#define BL_ (B_ * L_)
#define DELTA2 0.016f   // 2*delta; delta=0.008 >= rigorous bf16 dot bound (0.004) with 2x margin
#define QCAP 4096

typedef __attribute__((ext_vector_type(8))) short bf16x8;
typedef __attribute__((ext_vector_type(4))) float f32x4;

__device__ __forceinline__ void gload_lds16(const void* g, void* l) {
    __builtin_amdgcn_global_load_lds(
        (const __attribute__((address_space(1))) unsigned int*)g,
        (__attribute__((address_space(3))) unsigned int*)l, 16, 0, 0);
}

#define WAIT_VM(N) asm volatile("s_waitcnt vmcnt(" #N ")" ::: "memory")

// ---------------- K1: normalize + bf16 cast (round-0 linear mapping, proven) ----------------
__global__ void k_norm(const float* __restrict__ ctx,
                       float* __restrict__ cn, float* __restrict__ en,
                       ushort* __restrict__ cnb, ushort* __restrict__ enb) {
    int wid  = blockIdx.x * 4 + (threadIdx.x >> 6);   // 0..32767
    int lane = threadIdx.x & 63;
    int b   = wid >> 12;
    int rem = wid & 4095;
    int c   = rem >> 11;
    int l   = rem & 2047;

    const float* src = ctx + (size_t)wid * D_;
    float2 v = ((const float2*)src)[lane];
    float ss = v.x * v.x + v.y * v.y;
    #pragma unroll
    for (int off = 32; off; off >>= 1) ss += __shfl_down(ss, off, 64);
    ss = __shfl(ss, 0, 64);
    float n = fmaxf(sqrtf(ss), 1e-8f);
    float ox = v.x / n, oy = v.y / n;

    size_t ro = (size_t)(b * L_ + l) * D_;
    float* dst = (c == 0 ? cn : en) + ro;
    ((float2*)dst)[lane] = make_float2(ox, oy);

    __hip_bfloat16 hx = __float2bfloat16(ox), hy = __float2bfloat16(oy);
    ushort ux = *(ushort*)&hx, uy = *(ushort*)&hy;
    ushort* dstb = (c == 0 ? cnb : enb) + ro;
    ((ushort2*)dstb)[lane] = make_ushort2(ux, uy);
}

// ---------------- K2: fused sim + argmax (round-3 verified structure, unchanged) ----------------
__global__ __launch_bounds__(512, 2) void k_sim(const ushort* __restrict__ cnb,
                                                const ushort* __restrict__ enb,
                                                const float* __restrict__ cn,
                                                const float* __restrict__ en,
                                                int* __restrict__ finalidx) {
    __shared__ __align__(16) char Bsm[8][4][4096];   // 128 KB ring buffers
    __shared__ float wrowmax[8][64];
    __shared__ float rowth_l[64];
    __shared__ unsigned long long best[64];
    __shared__ int qbuf[QCAP];
    __shared__ int qn;

    const int bid = blockIdx.x;
    const int b = bid & 7, rb = bid >> 3;
    const int row0 = rb * 64;
    const int tid = threadIdx.x;
    const int wave = tid >> 6, lane = tid & 63;
    const int m = lane & 15, q = lane >> 4;

    if (tid == 0) qn = 0;
    if (tid < 64) best[tid] = 0ULL;

    const ushort* Ab = cnb + ((size_t)(b * L_) + row0) * D_;
    const char* gw = (const char*)(enb + (size_t)(b * L_) * D_) + (size_t)wave * 65536;
    char* Bw = &Bsm[wave][0][0];

    // A fragments: 64 rows x 128 k in registers for the whole kernel (64 VGPRs)
    bf16x8 Areg[16];
    #pragma unroll
    for (int rt = 0; rt < 4; ++rt)
        #pragma unroll
        for (int kc = 0; kc < 4; ++kc)
            Areg[rt * 4 + kc] = *(const bf16x8*)(Ab + (size_t)(rt * 16 + m) * D_ + kc * 32 + q * 8);

    // stage chunk c (16 cols = 4KB) into its ring slot, pre-swizzled global source
    auto STAGE = [&](int c) {
        const char* gc = gw + (size_t)c * 4096;
        char* lbuf = Bw + (c & 3) * 4096;
        #pragma unroll
        for (int i = 0; i < 4; ++i) {
            int j = i * 4 + q;                               // col within chunk
            int so = j * 256 + ((m ^ (j & 7)) << 4);         // swizzled source
            gload_lds16(gc + so, lbuf + i * 1024);           // linear LDS dest
        }
    };
    // 64 rows x 16 cols x 128 k; swizzled ds_read (conflict-free)
    auto TILE = [&](int c, f32x4 acc[4]) {
        const char* lbuf = Bw + (c & 3) * 4096;
        #pragma unroll
        for (int rt = 0; rt < 4; ++rt) acc[rt] = (f32x4){0.f, 0.f, 0.f, 0.f};
        #pragma unroll
        for (int kc = 0; kc < 4; ++kc) {
            bf16x8 bf = *(const bf16x8*)(lbuf + m * 256 + ((kc * 64 + q * 16) ^ ((m & 7) << 4)));
            #pragma unroll
            for (int rt = 0; rt < 4; ++rt)
                acc[rt] = __builtin_amdgcn_mfma_f32_16x16x32_bf16(Areg[rt * 4 + kc], bf, acc[rt], 0, 0, 0);
        }
    };

    float runmax[16];
    #pragma unroll
    for (int s = 0; s < 16; ++s) runmax[s] = -3.0e38f;

    auto FMAX = [&](const f32x4 acc[4]) {
        #pragma unroll
        for (int rt = 0; rt < 4; ++rt)
            #pragma unroll
            for (int reg = 0; reg < 4; ++reg)
                runmax[rt * 4 + reg] = fmaxf(runmax[rt * 4 + reg], acc[rt][reg]);
    };

    // ---------------- PASS 1 (forward): rowmax only ----------------
    STAGE(0); STAGE(1); STAGE(2);
    #pragma unroll 1
    for (int c = 0; c < 14; ++c) {
        WAIT_VM(8);                                    // stage c retired
        f32x4 acc[4];
        TILE(c, acc);
        if (c < 13) STAGE(c + 3);                      // ring slot (c-1)&3, free
        FMAX(acc);
    }
    { WAIT_VM(4); f32x4 acc[4]; TILE(14, acc); FMAX(acc); }
    { WAIT_VM(0); f32x4 acc[4]; TILE(15, acc); FMAX(acc); }

    // cross-lane (m) then cross-wave row-max reduction
    #pragma unroll
    for (int s = 0; s < 16; ++s) {
        float v = runmax[s];
        v = fmaxf(v, __shfl_xor(v, 1, 64));
        v = fmaxf(v, __shfl_xor(v, 2, 64));
        v = fmaxf(v, __shfl_xor(v, 4, 64));
        v = fmaxf(v, __shfl_xor(v, 8, 64));
        runmax[s] = v;
    }
    if (m == 0) {
        #pragma unroll
        for (int rt = 0; rt < 4; ++rt)
            #pragma unroll
            for (int reg = 0; reg < 4; ++reg)
                wrowmax[wave][rt * 16 + q * 4 + reg] = runmax[rt * 4 + reg];
    }
    __syncthreads();
    if (tid < 64) {
        float rm = wrowmax[0][tid];
        #pragma unroll
        for (int w = 1; w < 8; ++w) rm = fmaxf(rm, wrowmax[w][tid]);
        rowth_l[tid] = rm - DELTA2;
    }
    __syncthreads();
    float rowth_r[16];
    #pragma unroll
    for (int rt = 0; rt < 4; ++rt)
        #pragma unroll
        for (int reg = 0; reg < 4; ++reg)
            rowth_r[rt * 4 + reg] = rowth_l[rt * 16 + q * 4 + reg];

    auto CAPT = [&](int c, const f32x4 acc[4]) {
        int col = wave * 256 + c * 16 + m;
        #pragma unroll
        for (int rt = 0; rt < 4; ++rt)
            #pragma unroll
            for (int reg = 0; reg < 4; ++reg)
                if (acc[rt][reg] >= rowth_r[rt * 4 + reg]) {
                    int row = rt * 16 + q * 4 + reg;
                    int pos = atomicAdd(&qn, 1);
                    if (pos < QCAP) qbuf[pos] = (row << 12) | col;
                }
    };

    // ---------------- PASS 2 (reverse): recompute + capture ----------------
    // chunks 15..12 still resident (ring slots 3..0); stage S(11-d) after TILE(d)
    #pragma unroll 1
    for (int d = 0; d < 4; ++d) {
        f32x4 acc[4];
        TILE(15 - d, acc);
        STAGE(11 - d);
        CAPT(15 - d, acc);
    }
    #pragma unroll 1
    for (int d = 4; d < 13; ++d) {
        WAIT_VM(12);                                   // stage for chunk 15-d retired
        f32x4 acc[4];
        TILE(15 - d, acc);
        if (d < 12) STAGE(11 - d);
        CAPT(15 - d, acc);
    }
    { WAIT_VM(8); f32x4 acc[4]; TILE(2, acc); CAPT(2, acc); }
    { WAIT_VM(4); f32x4 acc[4]; TILE(1, acc); CAPT(1, acc); }
    { WAIT_VM(0); f32x4 acc[4]; TILE(0, acc); CAPT(0, acc); }
    __syncthreads();

    // ---------------- PASS 3: exact double dots, 4 candidates/wave ----------------
    int qtot = min(qn, QCAP);
    for (int e0 = wave * 4; e0 < qtot; e0 += 32) {
        int e = e0 + q;
        bool act = (e < qtot);
        int pc = qbuf[act ? e : (qtot - 1)];
        int rl = (pc >> 12) & 63, col = pc & 0xFFF;
        const float* ar = cn + ((size_t)(b * L_) + row0 + rl) * D_;
        const float* br = en + ((size_t)(b * L_) + col) * D_;
        float4 x0 = ((const float4*)ar)[m * 2], x1 = ((const float4*)ar)[m * 2 + 1];
        float4 y0 = ((const float4*)br)[m * 2], y1 = ((const float4*)br)[m * 2 + 1];
        double s = (double)x0.x * y0.x + (double)x0.y * y0.y +
                   (double)x0.z * y0.z + (double)x0.w * y0.w +
                   (double)x1.x * y1.x + (double)x1.y * y1.y +
                   (double)x1.z * y1.z + (double)x1.w * y1.w;
        s += __shfl_xor(s, 1, 64);
        s += __shfl_xor(s, 2, 64);
        s += __shfl_xor(s, 4, 64);
        s += __shfl_xor(s, 8, 64);
        if (act && m == 0) {
            unsigned long long ub = (unsigned long long)__double_as_longlong(s);
            ub = (ub & 0x8000000000000000ULL) ? ~ub : (ub | 0x8000000000000000ULL);
            ub = (ub & ~0x7FFULL) | (unsigned long long)(2047 - col);  // tie -> lowest col
            atomicMax(&best[rl], ub);
        }
    }
    __syncthreads();
    if (tid < 64)
        finalidx[b * L_ + row0 + tid] = 2047 - (int)(best[tid] & 0x7FFULL);
}

// ---------------- K3: fused MLP + output, 512 threads, 4 waves/SIMD ----------------
// grid 512: block handles 32 output rows R0..R0+31. Each thread-pair-row:
//   row ty (0..31)      = cn[b*2048 + l0 + ty]
//   row 32+ty           = en[b*2048 + finalidx[R0+ty]]   (gathered)
// out[R0+ty] = (MLP(cn-row)+b2) + (MLP(en-row)+b2).
// Same As/Bs k-permutation and tx/jj column order as the verified k_feval ->
// summation order preserved (fp32 deltas ~1e-7, far under tolerance).
__global__ __launch_bounds__(512) void k_mlp(
        const float* __restrict__ cn, const float* __restrict__ en,
        const int* __restrict__ finalidx,
        const float* __restrict__ W1, const float* __restrict__ b1,
        const float* __restrict__ W2, const float* __restrict__ b2,
        float* __restrict__ out) {
    __shared__ __align__(16) float As[32][68];
    __shared__ __align__(16) float Bs[32][132];
    __shared__ float redv[2][32][16];
    __shared__ int fidxs[32];

    int tid = threadIdx.x;
    int tx = tid & 15, ty = tid >> 4;          // ty 0..31
    int rr = tid >> 3, kg = tid & 7;           // A-stage: row 0..63, kgroup 0..7
    int R0 = blockIdx.x * 32;
    int b  = R0 >> 11;
    int l0 = R0 & 2047;

    if (tid < 32) fidxs[tid] = finalidx[R0 + tid];

    const float* cnr = cn + ((size_t)(b * L_) + l0) * D_;
    const float* enr = en + (size_t)(b * L_) * D_;

    float acc[2][8];
    #pragma unroll
    for (int i = 0; i < 2; ++i)
        #pragma unroll
        for (int j = 0; j < 8; ++j) acc[i][j] = 0.0f;

    for (int kc = 0; kc < 4; ++kc) {
        __syncthreads();                       // covers fidxs at kc==0, As/Bs reuse after
        {
            const float* srow = (rr < 32) ? (cnr + (size_t)rr * D_)
                                          : (enr + (size_t)fidxs[rr - 32] * D_);
            float4 v = *(const float4*)(srow + kc * 32 + kg * 4);
            As[kg][rr]      = v.x;
            As[8 + kg][rr]  = v.y;
            As[16 + kg][rr] = v.z;
            As[24 + kg][rr] = v.w;
        }
        {
            int kr = tid >> 4;                 // 0..31
            int phys = (kr & 3) * 8 + (kr >> 2);
            const float* srcp = W1 + (size_t)(kc * 32 + kr) * D_ + tx * 8;
            *(float4*)&Bs[phys][tx * 8]     = *(const float4*)(srcp);
            *(float4*)&Bs[phys][tx * 8 + 4] = *(const float4*)(srcp + 4);
        }
        __syncthreads();
        #pragma unroll
        for (int k = 0; k < 32; ++k) {
            float a0 = As[k][ty];              // broadcast reads (16 lanes/addr)
            float a1 = As[k][32 + ty];
            float bb[8];
            *(float4*)&bb[0] = *(const float4*)&Bs[k][tx * 4];
            *(float4*)&bb[4] = *(const float4*)&Bs[k][64 + tx * 4];
            #pragma unroll
            for (int j = 0; j < 8; ++j) {
                acc[0][j] = fmaf(a0, bb[j], acc[0][j]);
                acc[1][j] = fmaf(a1, bb[j], acc[1][j]);
            }
        }
    }

    float w2j[8], b1j[8];
    #pragma unroll
    for (int jj = 0; jj < 8; ++jj) {
        int c = (jj < 4) ? (tx * 4 + jj) : (64 + tx * 4 + (jj - 4));
        w2j[jj] = W2[c];
        b1j[jj] = b1[c];
    }
    float bias2 = b2[0];
    __syncthreads();
    #pragma unroll
    for (int i = 0; i < 2; ++i) {
        float s = 0.0f;
        #pragma unroll
        for (int jj = 0; jj < 8; ++jj)
            s += fmaxf(acc[i][jj] + b1j[jj], 0.0f) * w2j[jj];
        redv[i][ty][tx] = s;
    }
    __syncthreads();
    if (tid < 32) {
        float s0 = 0.0f, s1 = 0.0f;
        #pragma unroll
        for (int tt = 0; tt < 16; ++tt) { s0 += redv[0][tid][tt]; s1 += redv[1][tid][tt]; }
        out[R0 + tid] = (s0 + bias2) + (s1 + bias2);
    }
}

extern "C" void kernel_launch(void* const* d_in, const int* in_sizes, int n_in,
                              void* d_out, int out_size, void* d_ws, size_t ws_size,
                              hipStream_t stream) {
    const float* context = (const float*)d_in[0];
    const float* W1 = (const float*)d_in[1];
    const float* b1 = (const float*)d_in[2];
    const float* W2 = (const float*)d_in[3];
    const float* b2 = (const float*)d_in[4];
    float* out = (float*)d_out;

    char* ws = (char*)d_ws;
    float*  cn  = (float*)(ws);                  // 8 MB
    float*  en  = (float*)(ws + 8388608);        // 8 MB
    ushort* cnb = (ushort*)(ws + 16777216);      // 4 MB
    ushort* enb = (ushort*)(ws + 20971520);      // 4 MB
    int* finalidx = (int*)(ws + 25165824);       // 64 KB

    k_norm<<<8192, 256, 0, stream>>>(context, cn, en, cnb, enb);
    k_sim<<<256, 512, 0, stream>>>(cnb, enb, cn, en, finalidx);
    k_mlp<<<512, 512, 0, stream>>>(cn, en, finalidx, W1, b1, W2, b2, out);
}